// Round 13
// baseline (78.481 us; speedup 1.0000x reference)
//
#include <hip/hip_runtime.h>
#include <hip/hip_bf16.h>

#define B_ 8192
#define D_ 256
#define TINV 14.285714285714285f  /* 1/0.07 */
#define EPS_ 1e-8f
#define BK 32
#define NBLK 32            /* B_/256 rank blocks */
#define NT 64              /* B_/128 tiles per dim */
#define NTRI (NT*(NT+1)/2) /* 2080 upper-tri tiles (k_pairs) */
#define NGB 1056           /* sum_p (64-2p): 256-row-panel blocks (k_negsum) */

typedef short short8 __attribute__((ext_vector_type(8)));
typedef float f32x4 __attribute__((ext_vector_type(4)));

__device__ __forceinline__ void mfma_bf16(f32x4& acc, short8 a, short8 b) {
    asm("v_mfma_f32_16x16x32_bf16 %0, %1, %2, %0" : "+v"(acc) : "v"(a), "v"(b));
}

__device__ __forceinline__ void mfma_fence() {
    __builtin_amdgcn_sched_barrier(0);
    asm volatile("s_nop 7\ns_nop 7" ::);
}

__device__ __forceinline__ unsigned short f2bf(float x) {
    __hip_bfloat16 h = __float2bfloat16(x);
    return __builtin_bit_cast(unsigned short, h);
}

// upper-triangle decode: idx in [0,NTRI) -> (bi,bj), bj>=bi (k_pairs)
__device__ __forceinline__ void tri_decode(int idx, int& bi, int& bj) {
    int t = NTRI - 1 - idx;
    int u = (int)((sqrtf(8.f * (float)t + 1.f) - 1.f) * 0.5f);
    while (u * (u + 1) / 2 > t) --u;
    while ((u + 1) * (u + 2) / 2 <= t) ++u;
    bi = (NT - 1) - u;
    bj = (NT - 1) - (t - u * (u + 1) / 2);
}

// panel decode: idx in [0,NGB) -> (panel p, col tile bj), bj in [2p, 63]
__device__ __forceinline__ void panel_decode(int idx, int& p, int& bj) {
    int rem = idx, pp = 0;
    for (;;) {
        int nc = 64 - 2 * pp;
        if (rem < nc) break;
        rem -= nc;
        ++pp;
    }
    p = pp;
    bj = 2 * pp + rem;
}

// ---- stage a [rows x 32] bf16 tile: 1x16B load/thread, waves [0,nwaves) ----
// linear LDS dest (wave-uniform base + lane*16), inverse-swizzled source.
// 64 slots per wave -> wave w covers rows 16w..16w+15.
__device__ __forceinline__ void stage(const char* gbase, int row0, int k0,
                                      short* ldst, int lane, int wid) {
    int p = (wid << 6) + lane;            // 16B slot
    int row = p >> 2;
    int kb = (p & 3) ^ ((row >> 1) & 3);  // inverse swizzle on source
    const char* g = gbase + ((size_t)(row0 + row) * (D_ * 2) + (size_t)(k0 + kb * 8) * 2);
    __builtin_amdgcn_global_load_lds(
        (const __attribute__((address_space(1))) unsigned int*)g,
        (__attribute__((address_space(3))) unsigned int*)(ldst + ((size_t)wid << 9)),
        16, 0, 0);
}

// register-lean wave tile 32x64 -> acc[2][4]; b consumed immediately.
// Works for any wm (A rows wm*32..wm*32+31 within the staged A tile).
__device__ __forceinline__ void compute_step(const short* lA, const short* lB,
                                             int lane, int wm, int wn, f32x4 acc[2][4]) {
    int rl = lane & 15, kb = lane >> 4;
    short8 a[2];
#pragma unroll
    for (int m = 0; m < 2; ++m) {
        int row = wm * 32 + m * 16 + rl;
        a[m] = ((const short8*)lA)[row * 4 + (kb ^ ((row >> 1) & 3))];
    }
#pragma unroll
    for (int n = 0; n < 4; ++n) {
        int row = wn * 64 + n * 16 + rl;
        short8 b = ((const short8*)lB)[row * 4 + (kb ^ ((row >> 1) & 3))];
        mfma_bf16(acc[0][n], a[0], b);
        mfma_bf16(acc[1][n], a[1], b);
    }
}

#define PIPE_STEP(T, WAITS)                                                     \
    {                                                                           \
        asm volatile(WAITS ::: "memory");                                       \
        __builtin_amdgcn_sched_barrier(0);                                      \
        __builtin_amdgcn_s_barrier();                                           \
        __builtin_amdgcn_sched_barrier(0);                                      \
        if ((T) + 2 < 8) {                                                      \
            stage(enb, i0, ((T) + 2) * BK, lA[((T) + 2) % 3], lane, wid);       \
            stage(enb, j0, ((T) + 2) * BK, lB[((T) + 2) % 3], lane, wid);       \
        }                                                                       \
        compute_step(lA[(T) % 3], lB[(T) % 3], lane, wm, wn, acc);              \
    }

// 16-wave variant: A staged by all 16 waves (2 per-thread loads incl. B for
// waves 0-7; A-only for waves 8-15) -> per-wave counted waits differ.
#define NSTEP(T, WU, WL)                                                        \
    {                                                                           \
        if (wid < 8) { asm volatile("s_waitcnt vmcnt(" WU ")" ::: "memory"); }  \
        else         { asm volatile("s_waitcnt vmcnt(" WL ")" ::: "memory"); }  \
        __builtin_amdgcn_sched_barrier(0);                                      \
        __builtin_amdgcn_s_barrier();                                           \
        __builtin_amdgcn_sched_barrier(0);                                      \
        if ((T) + 2 < 8) {                                                      \
            stage(enb, i0, ((T) + 2) * BK, lA[((T) + 2) % 3], lane, wid);       \
            if (wid < 8) stage(enb, j0, ((T) + 2) * BK, lB[((T) + 2) % 3], lane, wid); \
        }                                                                       \
        compute_step(lA[(T) % 3], lB[(T) % 3], lane, wm, wn, acc);              \
    }

// ---- 3-buffer depth-2 pipelined 128x128 GEMM, 8 waves (k_pairs) ------------
__device__ __forceinline__ void gemm_pipe(const char* enb, int i0, int j0,
                                          short (*lA)[128 * BK], short (*lB)[128 * BK],
                                          int lane, int wid, int wm, int wn,
                                          f32x4 acc[2][4]) {
    stage(enb, i0, 0, lA[0], lane, wid);
    stage(enb, j0, 0, lB[0], lane, wid);
    stage(enb, i0, BK, lA[1], lane, wid);
    stage(enb, j0, BK, lB[1], lane, wid);      // 4 loads/thread in flight
    PIPE_STEP(0, "s_waitcnt vmcnt(2)")
    PIPE_STEP(1, "s_waitcnt vmcnt(2)")
    PIPE_STEP(2, "s_waitcnt vmcnt(2)")
    PIPE_STEP(3, "s_waitcnt vmcnt(2)")
    PIPE_STEP(4, "s_waitcnt vmcnt(2)")
    PIPE_STEP(5, "s_waitcnt vmcnt(2)")
    PIPE_STEP(6, "s_waitcnt vmcnt(2)")
    PIPE_STEP(7, "s_waitcnt vmcnt(0)")
    mfma_fence();
}

// ---- per-block label histograms + zero negsum/total (no memsets needed) ----
__global__ __launch_bounds__(256) void k_bhist(const int* __restrict__ labels,
                                               unsigned* __restrict__ blockhist,
                                               float* __restrict__ negsum,
                                               float* __restrict__ total) {
    __shared__ unsigned h[8];
    int b = blockIdx.x, t = threadIdx.x;
    if (t < 8) h[t] = 0;
    negsum[b * 256 + t] = 0.f;            // 32*256 == B_
    if (b == 0 && t == 0) *total = 0.f;
    __syncthreads();
    atomicAdd(&h[labels[b * 256 + t] & 7], 1u);
    __syncthreads();
    if (t < 8) blockhist[b * 8 + t] = h[t];
}

// ---- counting-sort rank (prefix recomputed per block in LDS) ---------------
__global__ __launch_bounds__(256) void k_pos(const int* __restrict__ labels,
                                             const unsigned* __restrict__ blockhist,
                                             unsigned* __restrict__ hist,
                                             int* __restrict__ pos) {
    __shared__ unsigned cnt[8][NBLK];
    __shared__ unsigned clsbase[8];
    __shared__ unsigned wcnt[4][8];
    int b = blockIdx.x, t = threadIdx.x;
    { int bb = t >> 3, c = t & 7; cnt[c][bb] = blockhist[bb * 8 + c]; }
    __syncthreads();
    if (t < 8) {
        unsigned run = 0;
        for (int b2 = 0; b2 < NBLK; ++b2) {
            unsigned v = cnt[t][b2];
            cnt[t][b2] = run;             // exclusive prefix across blocks
            run += v;
        }
        clsbase[t] = run;                 // class totals (temp)
        if (b == 0) hist[t] = run;
    }
    __syncthreads();
    if (t == 0) {
        unsigned run = 0;
        for (int c = 0; c < 8; ++c) {
            unsigned tot = clsbase[c];
            clsbase[c] = run;             // exclusive scan across classes
            run += tot;
        }
    }
    __syncthreads();
    int row = b * 256 + t;
    int c = labels[row] & 7;
    int lane = t & 63, w = t >> 6;
    unsigned long long lanebelow = (1ull << lane) - 1ull;
    unsigned myrank = 0;
#pragma unroll
    for (int cv = 0; cv < 8; ++cv) {
        unsigned long long mask = __ballot(c == cv);
        if (lane == 0) wcnt[w][cv] = (unsigned)__popcll(mask);
        if (c == cv) myrank = (unsigned)__popcll(mask & lanebelow);
    }
    __syncthreads();
    unsigned pre = 0;
    for (int wp = 0; wp < 4; ++wp) if (wp < w) pre += wcnt[wp][c];
    pos[row] = (int)(clsbase[c] + cnt[c][b] + pre + myrank);
}

// ---- normalize rows -> bf16, scatter to precomputed sorted position --------
__global__ __launch_bounds__(256) void k_scatter(const float* __restrict__ emb,
                                                 const int* __restrict__ labels,
                                                 const int* __restrict__ pos,
                                                 __hip_bfloat16* __restrict__ en_s,
                                                 int* __restrict__ lab_s) {
    int row = blockIdx.x * 4 + (threadIdx.x >> 6);
    int lane = threadIdx.x & 63;
    float4 v = reinterpret_cast<const float4*>(emb)[(size_t)row * 64 + lane];
    float ss = v.x * v.x + v.y * v.y + v.z * v.z + v.w * v.w;
#pragma unroll
    for (int off = 32; off >= 1; off >>= 1) ss += __shfl_xor(ss, off, 64);
    float scale = 1.0f / fmaxf(sqrtf(ss), 1e-12f);
    int p = pos[row];
    ushort4 o;
    o.x = f2bf(v.x * scale);
    o.y = f2bf(v.y * scale);
    o.z = f2bf(v.z * scale);
    o.w = f2bf(v.w * scale);
    reinterpret_cast<ushort4*>(en_s)[(size_t)p * 64 + lane] = o;
    if (lane == 0) lab_s[p] = labels[row] & 7;
}

// ---- pass A: 256x128 panel blocks, 16 waves, 2 blocks/CU -------------------
// Panel p = rows 256p..256p+255 (row-blocks 2p, 2p+1); cols bj in [2p,63].
// bj==2p:   upper half = diag tile (2p,2p); lower half = (2p+1,2p), the
//           transposed instance of pair (2p,2p+1) -> that pair never revisited.
// bj==2p+1: upper half masked (would duplicate); lower = diag (2p+1,2p+1).
// bj>=2p+2: both halves normal off-diag tiles.
// P keys: rowsums -> bj; colsums -> own row-block (2p for upper, 2p+1 lower).
// Coverage: every P[k][x] written exactly once (see analysis); k_red unchanged.
template <bool USEP>
__global__ __launch_bounds__(1024, 8) void k_negsum(const __hip_bfloat16* __restrict__ en,
                                                    const int* __restrict__ lab_s,
                                                    float* __restrict__ P,
                                                    float* __restrict__ negsum) {
    __shared__ short lA[3][256 * BK];   // 3 x 16 KB
    __shared__ short lB[3][128 * BK];   // 3 x 8 KB
    int p, bj;
    panel_decode(blockIdx.x, p, bj);
    int i0 = p * 256, j0 = bj * 128;
    int tid = threadIdx.x;
    int lane = tid & 63, wid = tid >> 6;        // 16 waves
    int wm = wid >> 1, wn = wid & 1;            // 8x2 grid of 32x64 wave-tiles
    int rl = lane & 15, rowg = (lane >> 4) * 4;
    const char* enb = (const char*)en;

    // labels -> registers, issued before stages (drained by first counted wait)
    int lj[4], li[2][4];
#pragma unroll
    for (int n = 0; n < 4; ++n) lj[n] = lab_s[j0 + wn * 64 + n * 16 + rl];
#pragma unroll
    for (int m = 0; m < 2; ++m)
#pragma unroll
        for (int r = 0; r < 4; ++r) li[m][r] = lab_s[i0 + wm * 32 + m * 16 + rowg + r];

    f32x4 acc[2][4] = {};
    stage(enb, i0, 0, lA[0], lane, wid);
    if (wid < 8) stage(enb, j0, 0, lB[0], lane, wid);
    stage(enb, i0, BK, lA[1], lane, wid);
    if (wid < 8) stage(enb, j0, BK, lB[1], lane, wid);
    NSTEP(0, "2", "1")
    NSTEP(1, "2", "1")
    NSTEP(2, "2", "1")
    NSTEP(3, "2", "1")
    NSTEP(4, "2", "1")
    NSTEP(5, "2", "1")
    NSTEP(6, "2", "1")
    NSTEP(7, "0", "0")
    mfma_fence();

    bool isU = (wm < 4);                        // rows in block 2p vs 2p+1
    bool doUblk = (bj != 2 * p + 1);            // upper half active?
    bool colU = (bj >= 2 * p + 2);              // upper half emits colsums?
    bool colL = (bj != 2 * p + 1);              // lower half emits colsums?
    bool doRow = isU ? doUblk : true;
    bool doCol = isU ? colU : colL;

    // scratch aliases lA[0] (sredR 2 KB) + lB[0] (sredC 4 KB); buf0 last read
    // at step 6 and all waves passed the step-7 barrier before epilogue.
    float* sredR = (float*)lA;   // [wn][row]: 2*256 floats
    float* sredC = (float*)lB;   // [wm][col]: 8*128 floats

    float cp[4] = {0.f, 0.f, 0.f, 0.f};
#pragma unroll
    for (int m = 0; m < 2; ++m) {
        float part[4];
#pragma unroll
        for (int r = 0; r < 4; ++r) {
            part[r] = 0.f;
#pragma unroll
            for (int n = 0; n < 4; ++n) {
                float e = (li[m][r] != lj[n]) ? __expf(acc[m][n][r] * TINV) : 0.f;
                part[r] += e;
                cp[n] += e;
            }
        }
#pragma unroll
        for (int off = 1; off < 16; off <<= 1)
#pragma unroll
            for (int r = 0; r < 4; ++r) part[r] += __shfl_xor(part[r], off, 64);
        if (rl == 0 && doRow) {
#pragma unroll
            for (int r = 0; r < 4; ++r) {
                int row = wm * 32 + m * 16 + rowg + r;       // 0..255
                if (USEP) sredR[wn * 256 + row] = part[r];
                else      atomicAdd(&negsum[i0 + row], part[r]);
            }
        }
    }
    // col partials (this wave covers rows wm*32..wm*32+31)
    if (doCol) {
#pragma unroll
        for (int n = 0; n < 4; ++n) {
            cp[n] += __shfl_xor(cp[n], 16, 64);
            cp[n] += __shfl_xor(cp[n], 32, 64);
            if (lane < 16) {
                int col = wn * 64 + n * 16 + lane;
                if (USEP) sredC[wm * 128 + col] = cp[n];
                else      atomicAdd(&negsum[j0 + col], cp[n]);
            }
        }
    }
    if (USEP) {
        __syncthreads();
        if (tid < 256) {                // rowsums, key bj
            if (tid >= 128 || doUblk)
                P[(size_t)bj * B_ + i0 + tid] = sredR[tid] + sredR[256 + tid];
        } else if (tid < 384) {         // colsums from upper half, key 2p
            int c = tid - 256;
            if (colU)
                P[(size_t)(2 * p) * B_ + j0 + c] =
                    sredC[c] + sredC[128 + c] + sredC[256 + c] + sredC[384 + c];
        } else if (tid < 512) {         // colsums from lower half, key 2p+1
            int c = tid - 384;
            if (colL)
                P[(size_t)(2 * p + 1) * B_ + j0 + c] =
                    sredC[512 + c] + sredC[640 + c] + sredC[768 + c] + sredC[896 + c];
        }
    }
}

// ---- reduce P -> negsum ----------------------------------------------------
__global__ __launch_bounds__(256) void k_red(const float* __restrict__ P,
                                             float* __restrict__ negsum) {
    int i = blockIdx.x * 256 + threadIdx.x;
    float s = 0.f;
#pragma unroll 8
    for (int k = 0; k < 64; ++k) s += P[(size_t)k * B_ + i];
    negsum[i] = s;
}

// ---- pass B: positive-pair loss over class-overlap tiles, 8 waves ----------
__global__ __launch_bounds__(512, 8) void k_pairs(const __hip_bfloat16* __restrict__ en,
                                                  const int* __restrict__ lab_s,
                                                  const float* __restrict__ negsum,
                                                  const unsigned* __restrict__ hist,
                                                  float* __restrict__ total) {
    int bi, bj;
    tri_decode(blockIdx.x, bi, bj);
    int i0 = bi * 128, j0 = bj * 128;
    // sorted labels: positives exist only if col-block min <= row-block max
    if (lab_s[j0] > lab_s[i0 + 127]) return;

    __shared__ short lA[3][128 * BK];
    __shared__ short lB[3][128 * BK];
    __shared__ int sLi[128], sLj[128];
    __shared__ float sNgI[128], sNgJ[128];
    int tid = threadIdx.x;
    if (tid < 128) {
        int l = lab_s[i0 + tid];
        unsigned h = hist[l];
        sLi[tid] = (h > 1u && h < (unsigned)B_) ? l : -1;
        sNgI[tid] = negsum[i0 + tid] + EPS_;
    } else if (tid < 256) {
        int idx = tid - 128;
        int l = lab_s[j0 + idx];
        unsigned h = hist[l];
        sLj[idx] = (h > 1u && h < (unsigned)B_) ? l : -1;
        sNgJ[idx] = negsum[j0 + idx] + EPS_;
    }
    __syncthreads();   // vmcnt baseline 0

    int lane = tid & 63, wid = tid >> 6;
    int wm = wid >> 1, wn = wid & 1;
    f32x4 acc[2][4] = {};
    gemm_pipe((const char*)en, i0, j0, lA, lB, lane, wid, wm, wn, acc);

    int rl = lane & 15, rowg = (lane >> 4) * 4;
    int lj[4];
    float ngJ[4];
#pragma unroll
    for (int n = 0; n < 4; ++n) {
        lj[n] = sLj[wn * 64 + n * 16 + rl];
        ngJ[n] = sNgJ[wn * 64 + n * 16 + rl];
    }

    bool offd = (bi != bj);
    float tot = 0.f;
#pragma unroll
    for (int m = 0; m < 2; ++m) {
#pragma unroll
        for (int r = 0; r < 4; ++r) {
            int ii = wm * 32 + m * 16 + rowg + r;
            int li = sLi[ii];
            float ngI = sNgI[ii];
#pragma unroll
            for (int n = 0; n < 4; ++n) {
                int jj = wn * 64 + n * 16 + rl;
                bool use = (li == lj[n]) && (li >= 0) && (offd || ii != jj);
                if (use) {
                    float s = acc[m][n][r] * TINV;
                    float e = __expf(s);
                    float t = __logf(e + ngI) - s;         // pair (i,j)
                    if (offd) t += __logf(e + ngJ[n]) - s; // mirrored pair (j,i)
                    tot += t;
                }
            }
        }
    }
#pragma unroll
    for (int off = 32; off >= 1; off >>= 1) tot += __shfl_xor(tot, off, 64);
    __shared__ float sred[8];
    if (lane == 0) sred[wid] = tot;
    __syncthreads();
    if (tid == 0) {
        float s = 0.f;
#pragma unroll
        for (int w = 0; w < 8; ++w) s += sred[w];
        atomicAdd(total, s);
    }
}

// ---- finalize: count = sum_c h(h-1) over valid classes ---------------------
__global__ __launch_bounds__(64) void k_final(const unsigned* __restrict__ hist,
                                              const float* __restrict__ total,
                                              float* __restrict__ out) {
    int t = threadIdx.x;
    unsigned c = 0;
    if (t < 8) {
        unsigned h = hist[t];
        if (h > 1u && h < (unsigned)B_) c = h * (h - 1u);
    }
#pragma unroll
    for (int off = 4; off >= 1; off >>= 1) c += (unsigned)__shfl_xor((int)c, off, 64);
    if (t == 0) out[0] = (c > 0u) ? total[0] / (float)c : 0.f;
}

extern "C" void kernel_launch(void* const* d_in, const int* in_sizes, int n_in,
                              void* d_out, int out_size, void* d_ws, size_t ws_size,
                              hipStream_t stream) {
    const float* emb = (const float*)d_in[0];
    const int* labels = (const int*)d_in[1];
    float* out = (float*)d_out;
    char* ws = (char*)d_ws;

    const size_t EN_BYTES = (size_t)B_ * D_ * 2;   // 4 MB
    __hip_bfloat16* en_s = (__hip_bfloat16*)ws;
    char* p = ws + EN_BYTES;
    float* negsum = (float*)p;            p += (size_t)B_ * 4;   // 32 KB
    int* lab_s = (int*)p;                 p += (size_t)B_ * 4;   // 32 KB
    int* pos = (int*)p;                   p += (size_t)B_ * 4;   // 32 KB
    unsigned* blockhist = (unsigned*)p;   p += NBLK * 8 * 4;     // 1 KB
    unsigned* hist = (unsigned*)p;        p += 64;
    float* total = (float*)p;             p += 64;
    float* P = (float*)p;                 // 2 MB, carved LAST
    size_t need = (size_t)(p - ws) + (size_t)NT * B_ * 4;
    bool bigws = ws_size >= need;

    k_bhist<<<NBLK, 256, 0, stream>>>(labels, blockhist, negsum, total);
    k_pos<<<NBLK, 256, 0, stream>>>(labels, blockhist, hist, pos);
    k_scatter<<<B_ / 4, 256, 0, stream>>>(emb, labels, pos, en_s, lab_s);
    if (bigws) {
        k_negsum<true><<<NGB, 1024, 0, stream>>>(en_s, lab_s, P, negsum);
        k_red<<<B_ / 256, 256, 0, stream>>>(P, negsum);
    } else {
        k_negsum<false><<<NGB, 1024, 0, stream>>>(en_s, lab_s, P, negsum);
    }
    k_pairs<<<NTRI, 512, 0, stream>>>(en_s, lab_s, negsum, hist, total);
    k_final<<<1, 64, 0, stream>>>(hist, total, out);
}

// Round 14
// 72.237 us; speedup vs baseline: 1.0864x; 1.0864x over previous
//
#include <hip/hip_runtime.h>
#include <hip/hip_bf16.h>

#define B_ 8192
#define D_ 256
#define TINV 14.285714285714285f  /* 1/0.07 */
#define EPS_ 1e-8f
#define BK 32
#define NBLK 32            /* B_/256 rank blocks */
#define NT 64              /* B_/128 tiles per dim */
#define NTRI (NT*(NT+1)/2) /* 2080 upper-tri tiles */

typedef short short8 __attribute__((ext_vector_type(8)));
typedef float f32x4 __attribute__((ext_vector_type(4)));

__device__ __forceinline__ void mfma_bf16(f32x4& acc, short8 a, short8 b) {
    asm("v_mfma_f32_16x16x32_bf16 %0, %1, %2, %0" : "+v"(acc) : "v"(a), "v"(b));
}

__device__ __forceinline__ void mfma_fence() {
    __builtin_amdgcn_sched_barrier(0);
    asm volatile("s_nop 7\ns_nop 7" ::);
}

__device__ __forceinline__ unsigned short f2bf(float x) {
    __hip_bfloat16 h = __float2bfloat16(x);
    return __builtin_bit_cast(unsigned short, h);
}

// upper-triangle decode: idx in [0,NTRI) -> (bi,bj), bj>=bi
__device__ __forceinline__ void tri_decode(int idx, int& bi, int& bj) {
    int t = NTRI - 1 - idx;
    int u = (int)((sqrtf(8.f * (float)t + 1.f) - 1.f) * 0.5f);
    while (u * (u + 1) / 2 > t) --u;
    while ((u + 1) * (u + 2) / 2 <= t) ++u;
    bi = (NT - 1) - u;
    bj = (NT - 1) - (t - u * (u + 1) / 2);
}

// ---- stage one 128x32 bf16 tile (8 KB), 512 threads: 1x16B load/thread -----
// linear LDS dest (wave-uniform base + lane*16), inverse-swizzled source.
__device__ __forceinline__ void stage(const char* gbase, int row0, int k0,
                                      short* ldst, int lane, int wid) {
    int p = (wid << 6) + lane;            // 16B-slot 0..511
    int row = p >> 2;
    int kb = (p & 3) ^ ((row >> 1) & 3);  // inverse swizzle on source
    const char* g = gbase + ((size_t)(row0 + row) * (D_ * 2) + (size_t)(k0 + kb * 8) * 2);
    __builtin_amdgcn_global_load_lds(
        (const __attribute__((address_space(1))) unsigned int*)g,
        (__attribute__((address_space(3))) unsigned int*)(ldst + ((size_t)wid << 9)),
        16, 0, 0);
}

// 8-wave, register-lean: wave (wm,wn) owns 32x64 -> acc[2][4]. b-fragments
// loaded one at a time and consumed immediately (peak live set: acc 32 +
// a 8 + b 4 + addr/labels ~20 < 64 VGPR -> the 8-waves/SIMD HW tier).
__device__ __forceinline__ void compute_step(const short* lA, const short* lB,
                                             int lane, int wm, int wn, f32x4 acc[2][4]) {
    int rl = lane & 15, kb = lane >> 4;
    short8 a[2];
#pragma unroll
    for (int m = 0; m < 2; ++m) {
        int row = wm * 32 + m * 16 + rl;
        a[m] = ((const short8*)lA)[row * 4 + (kb ^ ((row >> 1) & 3))];
    }
#pragma unroll
    for (int n = 0; n < 4; ++n) {
        int row = wn * 64 + n * 16 + rl;
        short8 b = ((const short8*)lB)[row * 4 + (kb ^ ((row >> 1) & 3))];
        mfma_bf16(acc[0][n], a[0], b);
        mfma_bf16(acc[1][n], a[1], b);
    }
}

#define PIPE_STEP(T, WAITS)                                                     \
    {                                                                           \
        asm volatile(WAITS ::: "memory");                                       \
        __builtin_amdgcn_sched_barrier(0);                                      \
        __builtin_amdgcn_s_barrier();                                           \
        __builtin_amdgcn_sched_barrier(0);                                      \
        if ((T) + 2 < 8) {                                                      \
            stage(enb, i0, ((T) + 2) * BK, lA[((T) + 2) % 3], lane, wid);       \
            stage(enb, j0, ((T) + 2) * BK, lB[((T) + 2) % 3], lane, wid);       \
        }                                                                       \
        compute_step(lA[(T) % 3], lB[(T) % 3], lane, wm, wn, acc);              \
    }

// ---- 3-buffer depth-2 pipelined 128x128 GEMM, 8 waves (round-10 schedule) --
__device__ __forceinline__ void gemm_pipe(const char* enb, int i0, int j0,
                                          short (*lA)[128 * BK], short (*lB)[128 * BK],
                                          int lane, int wid, int wm, int wn,
                                          f32x4 acc[2][4]) {
    // precondition: vmcnt drains to 0 via the counted waits below even if the
    // caller issued older VMEM ops first (oldest-first retirement).
    stage(enb, i0, 0, lA[0], lane, wid);
    stage(enb, j0, 0, lB[0], lane, wid);
    stage(enb, i0, BK, lA[1], lane, wid);
    stage(enb, j0, BK, lB[1], lane, wid);      // 4 loads/thread in flight
    PIPE_STEP(0, "s_waitcnt vmcnt(2)")
    PIPE_STEP(1, "s_waitcnt vmcnt(2)")
    PIPE_STEP(2, "s_waitcnt vmcnt(2)")
    PIPE_STEP(3, "s_waitcnt vmcnt(2)")
    PIPE_STEP(4, "s_waitcnt vmcnt(2)")
    PIPE_STEP(5, "s_waitcnt vmcnt(2)")
    PIPE_STEP(6, "s_waitcnt vmcnt(2)")
    PIPE_STEP(7, "s_waitcnt vmcnt(0)")
    mfma_fence();
}

// ---- per-block label histograms + zero negsum/total (no memsets needed) ----
__global__ __launch_bounds__(256) void k_bhist(const int* __restrict__ labels,
                                               unsigned* __restrict__ blockhist,
                                               float* __restrict__ negsum,
                                               float* __restrict__ total) {
    __shared__ unsigned h[8];
    int b = blockIdx.x, t = threadIdx.x;
    if (t < 8) h[t] = 0;
    negsum[b * 256 + t] = 0.f;            // 32*256 == B_
    if (b == 0 && t == 0) *total = 0.f;
    __syncthreads();
    atomicAdd(&h[labels[b * 256 + t] & 7], 1u);
    __syncthreads();
    if (t < 8) blockhist[b * 8 + t] = h[t];
}

// ---- counting-sort rank (prefix recomputed per block in LDS) ---------------
__global__ __launch_bounds__(256) void k_pos(const int* __restrict__ labels,
                                             const unsigned* __restrict__ blockhist,
                                             unsigned* __restrict__ hist,
                                             int* __restrict__ pos) {
    __shared__ unsigned cnt[8][NBLK];
    __shared__ unsigned clsbase[8];
    __shared__ unsigned wcnt[4][8];
    int b = blockIdx.x, t = threadIdx.x;
    { int bb = t >> 3, c = t & 7; cnt[c][bb] = blockhist[bb * 8 + c]; }
    __syncthreads();
    if (t < 8) {
        unsigned run = 0;
        for (int b2 = 0; b2 < NBLK; ++b2) {
            unsigned v = cnt[t][b2];
            cnt[t][b2] = run;             // exclusive prefix across blocks
            run += v;
        }
        clsbase[t] = run;                 // class totals (temp)
        if (b == 0) hist[t] = run;
    }
    __syncthreads();
    if (t == 0) {
        unsigned run = 0;
        for (int c = 0; c < 8; ++c) {
            unsigned tot = clsbase[c];
            clsbase[c] = run;             // exclusive scan across classes
            run += tot;
        }
    }
    __syncthreads();
    int row = b * 256 + t;
    int c = labels[row] & 7;
    int lane = t & 63, w = t >> 6;
    unsigned long long lanebelow = (1ull << lane) - 1ull;
    unsigned myrank = 0;
#pragma unroll
    for (int cv = 0; cv < 8; ++cv) {
        unsigned long long mask = __ballot(c == cv);
        if (lane == 0) wcnt[w][cv] = (unsigned)__popcll(mask);
        if (c == cv) myrank = (unsigned)__popcll(mask & lanebelow);
    }
    __syncthreads();
    unsigned pre = 0;
    for (int wp = 0; wp < 4; ++wp) if (wp < w) pre += wcnt[wp][c];
    pos[row] = (int)(clsbase[c] + cnt[c][b] + pre + myrank);
}

// ---- normalize rows -> bf16, scatter to precomputed sorted position --------
__global__ __launch_bounds__(256) void k_scatter(const float* __restrict__ emb,
                                                 const int* __restrict__ labels,
                                                 const int* __restrict__ pos,
                                                 __hip_bfloat16* __restrict__ en_s,
                                                 int* __restrict__ lab_s) {
    int row = blockIdx.x * 4 + (threadIdx.x >> 6);
    int lane = threadIdx.x & 63;
    float4 v = reinterpret_cast<const float4*>(emb)[(size_t)row * 64 + lane];
    float ss = v.x * v.x + v.y * v.y + v.z * v.z + v.w * v.w;
#pragma unroll
    for (int off = 32; off >= 1; off >>= 1) ss += __shfl_xor(ss, off, 64);
    float scale = 1.0f / fmaxf(sqrtf(ss), 1e-12f);
    int p = pos[row];
    ushort4 o;
    o.x = f2bf(v.x * scale);
    o.y = f2bf(v.y * scale);
    o.z = f2bf(v.z * scale);
    o.w = f2bf(v.w * scale);
    reinterpret_cast<ushort4*>(en_s)[(size_t)p * 64 + lane] = o;
    if (lane == 0) lab_s[p] = labels[row] & 7;
}

// ---- pass A: negsum partials, 8 waves, no preamble barrier -----------------
// Per-lane labels issued FIRST (oldest VMEM) -> they retire inside step-0's
// vmcnt(2) wait at zero extra cost; stages issue ~20 cycles into the block.
// Epilogue: collision-free P stores (USEP) via LDS scratch; P[k][x] is fully
// covered (x<128(k+1) by row-keys incl diag; x>=128(k+1) by col-keys).
template <bool USEP>
__global__ __launch_bounds__(512, 8) void k_negsum(const __hip_bfloat16* __restrict__ en,
                                                   const int* __restrict__ lab_s,
                                                   float* __restrict__ P,
                                                   float* __restrict__ negsum) {
    __shared__ short lA[3][128 * BK];
    __shared__ short lB[3][128 * BK];
    int bi, bj;
    tri_decode(blockIdx.x, bi, bj);
    int i0 = bi * 128, j0 = bj * 128;
    int tid = threadIdx.x;
    int lane = tid & 63, wid = tid >> 6;
    int wm = wid >> 1, wn = wid & 1;         // 4x2 grid of 32x64 wave-tiles
    int rl = lane & 15, rowg = (lane >> 4) * 4;
    const char* enb = (const char*)en;

    // labels -> registers, issued before any stage (drained by vmcnt(2) @ step 0)
    int lj[4], li[2][4];
#pragma unroll
    for (int n = 0; n < 4; ++n) lj[n] = lab_s[j0 + wn * 64 + n * 16 + rl];
#pragma unroll
    for (int m = 0; m < 2; ++m)
#pragma unroll
        for (int r = 0; r < 4; ++r) li[m][r] = lab_s[i0 + wm * 32 + m * 16 + rowg + r];

    f32x4 acc[2][4] = {};
    stage(enb, i0, 0, lA[0], lane, wid);
    stage(enb, j0, 0, lB[0], lane, wid);
    stage(enb, i0, BK, lA[1], lane, wid);
    stage(enb, j0, BK, lB[1], lane, wid);
    PIPE_STEP(0, "s_waitcnt vmcnt(2)")
    PIPE_STEP(1, "s_waitcnt vmcnt(2)")
    PIPE_STEP(2, "s_waitcnt vmcnt(2)")
    PIPE_STEP(3, "s_waitcnt vmcnt(2)")
    PIPE_STEP(4, "s_waitcnt vmcnt(2)")
    PIPE_STEP(5, "s_waitcnt vmcnt(2)")
    PIPE_STEP(6, "s_waitcnt vmcnt(2)")
    PIPE_STEP(7, "s_waitcnt vmcnt(0)")
    mfma_fence();

    // scratch aliases lA[0] (1 KB) + lB[0] (2 KB); buf0 last read at step 6,
    // all waves passed barrier(7) before any epilogue write.
    float* sredR = (float*)lA;   // [wn][row]: 2*128 floats
    float* sredC = (float*)lB;   // [wm][col]: 4*128 floats

    float cp[4] = {0.f, 0.f, 0.f, 0.f};
#pragma unroll
    for (int m = 0; m < 2; ++m) {
        float part[4];
#pragma unroll
        for (int r = 0; r < 4; ++r) {
            part[r] = 0.f;
#pragma unroll
            for (int n = 0; n < 4; ++n) {
                float e = (li[m][r] != lj[n]) ? __expf(acc[m][n][r] * TINV) : 0.f;
                part[r] += e;
                cp[n] += e;
            }
        }
#pragma unroll
        for (int off = 1; off < 16; off <<= 1)
#pragma unroll
            for (int r = 0; r < 4; ++r) part[r] += __shfl_xor(part[r], off, 64);
        if (rl == 0) {
#pragma unroll
            for (int r = 0; r < 4; ++r) {
                int row = wm * 32 + m * 16 + rowg + r;
                if (USEP) sredR[wn * 128 + row] = part[r];
                else      atomicAdd(&negsum[i0 + row], part[r]);
            }
        }
    }
    // col partial sums (this wave covers rows wm*32..wm*32+31)
    if (bi != bj) {
#pragma unroll
        for (int n = 0; n < 4; ++n) {
            cp[n] += __shfl_xor(cp[n], 16, 64);
            cp[n] += __shfl_xor(cp[n], 32, 64);
            if (lane < 16) {
                int col = wn * 64 + n * 16 + lane;
                if (USEP) sredC[wm * 128 + col] = cp[n];
                else      atomicAdd(&negsum[j0 + col], cp[n]);
            }
        }
    }
    if (USEP) {
        __syncthreads();
        // P[k][x]: x<128(k+1) from tile(bi,k) rows; x>=128(k+1) from tile(k,bj) cols.
        if (tid < 128)
            P[(size_t)bj * B_ + i0 + tid] = sredR[tid] + sredR[128 + tid];
        else if (tid < 256 && bi != bj) {
            int c = tid - 128;
            P[(size_t)bi * B_ + j0 + c] =
                sredC[c] + sredC[128 + c] + sredC[256 + c] + sredC[384 + c];
        }
    }
}

// ---- pass B: positive-pair loss over class-overlap tiles, 8 waves ----------
// USEP: negsum computed in-preamble from P (k_red folded in; P is L2-hot).
template <bool USEP>
__global__ __launch_bounds__(512, 8) void k_pairs(const __hip_bfloat16* __restrict__ en,
                                                  const int* __restrict__ lab_s,
                                                  const float* __restrict__ P,
                                                  const float* __restrict__ negsum,
                                                  const unsigned* __restrict__ hist,
                                                  float* __restrict__ total) {
    int bi, bj;
    tri_decode(blockIdx.x, bi, bj);
    int i0 = bi * 128, j0 = bj * 128;
    // sorted labels: positives exist only if col-block min <= row-block max
    if (lab_s[j0] > lab_s[i0 + 127]) return;

    __shared__ short lA[3][128 * BK];
    __shared__ short lB[3][128 * BK];
    __shared__ int sLi[128], sLj[128];
    __shared__ float sNgI[128], sNgJ[128];
    int tid = threadIdx.x;
    if (tid < 256) {
        int x = (tid < 128) ? (i0 + tid) : (j0 + tid - 128);
        int l = lab_s[x];
        unsigned h = hist[l];
        int lv = (h > 1u && h < (unsigned)B_) ? l : -1;
        float ng;
        if (USEP) {
            float s = 0.f;
#pragma unroll 8
            for (int k = 0; k < 64; ++k) s += P[(size_t)k * B_ + x];
            ng = s + EPS_;
        } else {
            ng = negsum[x] + EPS_;
        }
        if (tid < 128) { sLi[tid] = lv; sNgI[tid] = ng; }
        else           { sLj[tid - 128] = lv; sNgJ[tid - 128] = ng; }
    }
    __syncthreads();   // all preamble VMEM retired (values consumed into LDS)

    int lane = tid & 63, wid = tid >> 6;
    int wm = wid >> 1, wn = wid & 1;
    f32x4 acc[2][4] = {};
    gemm_pipe((const char*)en, i0, j0, lA, lB, lane, wid, wm, wn, acc);

    int rl = lane & 15, rowg = (lane >> 4) * 4;
    int lj[4];
    float ngJ[4];
#pragma unroll
    for (int n = 0; n < 4; ++n) {
        lj[n] = sLj[wn * 64 + n * 16 + rl];
        ngJ[n] = sNgJ[wn * 64 + n * 16 + rl];
    }

    bool offd = (bi != bj);
    float tot = 0.f;
#pragma unroll
    for (int m = 0; m < 2; ++m) {
#pragma unroll
        for (int r = 0; r < 4; ++r) {
            int ii = wm * 32 + m * 16 + rowg + r;
            int li = sLi[ii];
            float ngI = sNgI[ii];
#pragma unroll
            for (int n = 0; n < 4; ++n) {
                int jj = wn * 64 + n * 16 + rl;
                bool use = (li == lj[n]) && (li >= 0) && (offd || ii != jj);
                if (use) {
                    float s = acc[m][n][r] * TINV;
                    float e = __expf(s);
                    float t = __logf(e + ngI) - s;         // pair (i,j)
                    if (offd) t += __logf(e + ngJ[n]) - s; // mirrored pair (j,i)
                    tot += t;
                }
            }
        }
    }
#pragma unroll
    for (int off = 32; off >= 1; off >>= 1) tot += __shfl_xor(tot, off, 64);
    __shared__ float sred[8];
    if (lane == 0) sred[wid] = tot;
    __syncthreads();
    if (tid == 0) {
        float s = 0.f;
#pragma unroll
        for (int w = 0; w < 8; ++w) s += sred[w];
        atomicAdd(total, s);
    }
}

// ---- finalize: count = sum_c h(h-1) over valid classes ---------------------
__global__ __launch_bounds__(64) void k_final(const unsigned* __restrict__ hist,
                                              const float* __restrict__ total,
                                              float* __restrict__ out) {
    int t = threadIdx.x;
    unsigned c = 0;
    if (t < 8) {
        unsigned h = hist[t];
        if (h > 1u && h < (unsigned)B_) c = h * (h - 1u);
    }
#pragma unroll
    for (int off = 4; off >= 1; off >>= 1) c += (unsigned)__shfl_xor((int)c, off, 64);
    if (t == 0) out[0] = (c > 0u) ? total[0] / (float)c : 0.f;
}

extern "C" void kernel_launch(void* const* d_in, const int* in_sizes, int n_in,
                              void* d_out, int out_size, void* d_ws, size_t ws_size,
                              hipStream_t stream) {
    const float* emb = (const float*)d_in[0];
    const int* labels = (const int*)d_in[1];
    float* out = (float*)d_out;
    char* ws = (char*)d_ws;

    const size_t EN_BYTES = (size_t)B_ * D_ * 2;   // 4 MB
    __hip_bfloat16* en_s = (__hip_bfloat16*)ws;
    char* p = ws + EN_BYTES;
    float* negsum = (float*)p;            p += (size_t)B_ * 4;   // 32 KB
    int* lab_s = (int*)p;                 p += (size_t)B_ * 4;   // 32 KB
    int* pos = (int*)p;                   p += (size_t)B_ * 4;   // 32 KB
    unsigned* blockhist = (unsigned*)p;   p += NBLK * 8 * 4;     // 1 KB
    unsigned* hist = (unsigned*)p;        p += 64;
    float* total = (float*)p;             p += 64;
    float* P = (float*)p;                 // 2 MB, carved LAST
    size_t need = (size_t)(p - ws) + (size_t)NT * B_ * 4;
    bool bigws = ws_size >= need;

    k_bhist<<<NBLK, 256, 0, stream>>>(labels, blockhist, negsum, total);
    k_pos<<<NBLK, 256, 0, stream>>>(labels, blockhist, hist, pos);
    k_scatter<<<B_ / 4, 256, 0, stream>>>(emb, labels, pos, en_s, lab_s);
    if (bigws) {
        k_negsum<true><<<NTRI, 512, 0, stream>>>(en_s, lab_s, P, negsum);
        k_pairs<true><<<NTRI, 512, 0, stream>>>(en_s, lab_s, P, negsum, hist, total);
    } else {
        k_negsum<false><<<NTRI, 512, 0, stream>>>(en_s, lab_s, P, negsum);
        k_pairs<false><<<NTRI, 512, 0, stream>>>(en_s, lab_s, P, negsum, hist, total);
    }
    k_final<<<1, 64, 0, stream>>>(hist, total, out);
}